// Round 10
// baseline (1481.011 us; speedup 1.0000x reference)
//
#include <hip/hip_runtime.h>

#define B 16
#define N 8192
#define S1 512
#define S2 128
#define K 64

// ---------------------------------------------------------------------------
// DPP max step: wm = max(wm, dpp_shift(wm)). Value-only.
// ---------------------------------------------------------------------------
template<int CTRL>
__device__ __forceinline__ float dpp_max_f32(float v) {
  unsigned o = (unsigned)__builtin_amdgcn_update_dpp(
      (int)__float_as_uint(v), (int)__float_as_uint(v), CTRL, 0xF, 0xF, false);
  return fmaxf(v, __uint_as_float(o));
}

__device__ __forceinline__ float wave_max_bcast(float v) {
  v = dpp_max_f32<0x111>(v);  // row_shr:1
  v = dpp_max_f32<0x112>(v);  // row_shr:2
  v = dpp_max_f32<0x114>(v);  // row_shr:4
  v = dpp_max_f32<0x118>(v);  // row_shr:8
  v = dpp_max_f32<0x142>(v);  // row_bcast:15
  v = dpp_max_f32<0x143>(v);  // row_bcast:31 -> lane 63 holds wave max
  return __uint_as_float((unsigned)__builtin_amdgcn_readlane(
      (int)__float_as_uint(v), 63));  // SGPR broadcast to all lanes
}

// ---------------------------------------------------------------------------
// FPS stage 1 (multi-wave), FROZEN at the proven R13 config (450us, VGPR 52,
// 4w/SIMD issue-saturated = structural floor per the R15 config map).
// Key = (dist_bits<<32)|~idx; max ~idx == min idx == jnp.argmax first-occur.
// ---------------------------------------------------------------------------
template<int NT, int PT, int MAXP, int MAXN>
__device__ __forceinline__ void fps_body(
    const float* __restrict__ pts, float* __restrict__ out_xyz,
    float* __restrict__ out2, int out2_stride, int n, int npoint) {
  const int b = blockIdx.x;
  const int t = threadIdx.x;
  const int w = t >> 6;
  const float* base = pts + (size_t)b * n * 3;
  __shared__ unsigned long long cell[3][4];
  __shared__ float s_out[MAXP * 3];
  __shared__ float s_pts[MAXN * 3];
  if (t < 12) ((unsigned long long*)cell)[t] = 0ull;
  float px[PT], py[PT], pz[PT], mind[PT];
#pragma unroll
  for (int i = 0; i < PT; i++) {
    int p = t + i * NT;
    px[i] = base[p * 3 + 0];
    py[i] = base[p * 3 + 1];
    pz[i] = base[p * 3 + 2];
    mind[i] = 1e10f;
    s_pts[p * 3 + 0] = px[i];
    s_pts[p * 3 + 1] = py[i];
    s_pts[p * 3 + 2] = pz[i];
  }
  float cx = base[0], cy = base[1], cz = base[2];
  __syncthreads();
  for (int it = 0; it < npoint; it++) {
    if (t == 0) {
      s_out[it * 3 + 0] = cx; s_out[it * 3 + 1] = cy; s_out[it * 3 + 2] = cz;
    }
    float bv = -1.0f;
#pragma unroll
    for (int i = 0; i < PT; i++) {
      float dx = px[i] - cx, dy = py[i] - cy, dz = pz[i] - cz;
      float d = dx * dx;
      d = fmaf(dy, dy, d);
      d = fmaf(dz, dz, d);
      float md = fminf(mind[i], d);
      mind[i] = md;
      bv = fmaxf(bv, md);
    }
    float gm = wave_max_bcast(bv);
    if (bv == gm) {
      int bi = 0;
#pragma unroll
      for (int i = PT - 1; i >= 0; i--)
        if (mind[i] == bv) bi = i;  // downward sweep -> smallest i survives
      unsigned long long kk = ((unsigned long long)__float_as_uint(bv) << 32) |
                              (~(unsigned)(t + bi * NT));
      atomicMax(&cell[it % 3][w & 3], kk);
    }
    if (t < 4) cell[(it + 1) % 3][t] = 0ull;
    __syncthreads();
    unsigned long long k0 = cell[it % 3][0];
    unsigned long long k1 = cell[it % 3][1];
    unsigned long long k2 = cell[it % 3][2];
    unsigned long long k3 = cell[it % 3][3];
    unsigned long long wk = k0 > k1 ? k0 : k1;
    unsigned long long wk2 = k2 > k3 ? k2 : k3;
    if (wk2 > wk) wk = wk2;
    int ui = __builtin_amdgcn_readfirstlane((int)(~(unsigned)wk));
    const float* q = s_pts + ui * 3;
    cx = q[0]; cy = q[1]; cz = q[2];
  }
  for (int e = t; e < npoint * 3; e += NT)
    out_xyz[(size_t)b * npoint * 3 + e] = s_out[e];
  if (out2) {
    for (int e = t; e < npoint; e += NT) {
      float* o2 = out2 + ((size_t)b * npoint + e) * out2_stride;
      o2[0] = s_out[e * 3 + 0];
      o2[1] = s_out[e * 3 + 1];
      o2[2] = s_out[e * 3 + 2];
    }
  }
}

__global__ __launch_bounds__(1024) __attribute__((amdgpu_waves_per_eu(4, 4)))
void fps1_kernel(const float* __restrict__ pts, float* __restrict__ out_xyz,
                 float* __restrict__ out2, int out2_stride, int n, int npoint) {
  fps_body<1024, 8, 512, 8192>(pts, out_xyz, out2, out2_stride, n, npoint);
}

// ---------------------------------------------------------------------------
// FPS stage 2 — single wave, barrier-free (R16, verified). DS ops in one
// wave execute in program order: atomicMax -> fence -> ds_read -> clear.
// ---------------------------------------------------------------------------
template<int PT, int MAXP, int MAXN>
__global__ __launch_bounds__(64) __attribute__((amdgpu_waves_per_eu(1, 1)))
void fps_wave_kernel(const float* __restrict__ pts, float* __restrict__ out_xyz,
                     float* __restrict__ out2, int out2_stride, int n, int npoint) {
  const int b = blockIdx.x;
  const int t = threadIdx.x;
  const float* base = pts + (size_t)b * n * 3;
  __shared__ unsigned long long cell[2];
  __shared__ float s_out[MAXP * 3];
  __shared__ float s_pts[MAXN * 3];
  if (t < 2) cell[t] = 0ull;
  float px[PT], py[PT], pz[PT], mind[PT];
#pragma unroll
  for (int i = 0; i < PT; i++) {
    int p = t + i * 64;
    px[i] = base[p * 3 + 0];
    py[i] = base[p * 3 + 1];
    pz[i] = base[p * 3 + 2];
    mind[i] = 1e10f;
    s_pts[p * 3 + 0] = px[i];
    s_pts[p * 3 + 1] = py[i];
    s_pts[p * 3 + 2] = pz[i];
  }
  float cx = base[0], cy = base[1], cz = base[2];
  for (int it = 0; it < npoint; it++) {
    if (t == 0) {
      s_out[it * 3 + 0] = cx; s_out[it * 3 + 1] = cy; s_out[it * 3 + 2] = cz;
    }
    float bv = -1.0f;
#pragma unroll
    for (int i = 0; i < PT; i++) {
      float dx = px[i] - cx, dy = py[i] - cy, dz = pz[i] - cz;
      float d = dx * dx;
      d = fmaf(dy, dy, d);
      d = fmaf(dz, dz, d);
      float md = fminf(mind[i], d);
      mind[i] = md;
      bv = fmaxf(bv, md);
    }
    float gm = wave_max_bcast(bv);
    if (bv == gm) {
      int bi = 0;
#pragma unroll
      for (int i = PT - 1; i >= 0; i--)
        if (mind[i] == bv) bi = i;
      unsigned long long kk = ((unsigned long long)__float_as_uint(bv) << 32) |
                              (~(unsigned)(t + bi * 64));
      atomicMax(&cell[it & 1], kk);
    }
    __threadfence_block();
    unsigned long long wk = cell[it & 1];
    if (t == 0) cell[(it + 1) & 1] = 0ull;
    int ui = __builtin_amdgcn_readfirstlane((int)(~(unsigned)wk));
    const float* q = s_pts + ui * 3;
    cx = q[0]; cy = q[1]; cz = q[2];
  }
  for (int e = t; e < npoint * 3; e += 64)
    out_xyz[(size_t)b * npoint * 3 + e] = s_out[e];
  if (out2) {
    for (int e = t; e < npoint; e += 64) {
      float* o2 = out2 + ((size_t)b * npoint + e) * out2_stride;
      o2[0] = s_out[e * 3 + 0];
      o2[1] = s_out[e * 3 + 1];
      o2[2] = s_out[e * 3 + 2];
    }
  }
}

// ---------------------------------------------------------------------------
// Fused ball-query scan (ROUND-17): the block's 4 waves scan 4 contiguous
// index-quarters in parallel; each collects up to K in-radius hits in index
// order (ballot compaction, early exit at K). first-K-overall = concat of
// per-quarter ordered lists truncated at K (any global first-K element is
// within its quarter's first K). Tail-fill applies iff total < K — exact,
// because a truncated quarter reports cnt >= K. Distance formula and strict
// '<' kept bit-identical to the (passing) standalone ballq kernel.
// Writes merged idx for k = tid < K via the provided lambda-ish epilogue.
// ---------------------------------------------------------------------------
template<int NPTS>
__device__ __forceinline__ int ballq_fused(
    const float* __restrict__ pb, float cx, float cy, float cz, float r2,
    int tid, int* s_hits /*[4*K]*/, int* s_cnt /*[4]*/, int* s_first /*[4]*/) {
  const int w = tid >> 6, lane = tid & 63;
  const float sc = cx * cx + cy * cy + cz * cz;
  constexpr int QUARTER = NPTS / 4;
  int cnt = 0, first = 0x7fffffff;
  const int qbase = w * QUARTER;
  for (int base = qbase; base < qbase + QUARTER && cnt < K; base += 64) {
    int p = base + lane;
    float x = pb[p * 3 + 0], y = pb[p * 3 + 1], z = pb[p * 3 + 2];
    float sp = x * x + y * y + z * z;
    float dot = cx * x + cy * y + cz * z;
    float d2 = sc + sp - 2.0f * dot;
    bool inr = d2 < r2;
    unsigned long long m = __ballot(inr);
    if (first == 0x7fffffff && m != 0ull) first = base + __ffsll((long long)m) - 1;
    int pre = (int)__popcll(m & ((1ull << lane) - 1ull));
    if (inr && (cnt + pre) < K) s_hits[w * K + cnt + pre] = p;
    cnt += (int)__popcll(m);
  }
  if (lane == 0) { s_cnt[w] = cnt; s_first[w] = first; }
  __syncthreads();
  // merge for k = tid (< K); caller guards tid < K
  int cc0 = s_cnt[0] < K ? s_cnt[0] : K;
  int cc1 = s_cnt[1] < K ? s_cnt[1] : K;
  int cc2 = s_cnt[2] < K ? s_cnt[2] : K;
  int cc3 = s_cnt[3] < K ? s_cnt[3] : K;
  int k = tid;
  int idxk;
  if (k < cc0) idxk = s_hits[0 * K + k];
  else if (k < cc0 + cc1) idxk = s_hits[1 * K + k - cc0];
  else if (k < cc0 + cc1 + cc2) idxk = s_hits[2 * K + k - cc0 - cc1];
  else if (k < cc0 + cc1 + cc2 + cc3) idxk = s_hits[3 * K + k - cc0 - cc1 - cc2];
  else {
    int f01 = s_first[0] < s_first[1] ? s_first[0] : s_first[1];
    int f23 = s_first[2] < s_first[3] ? s_first[2] : s_first[3];
    int f = f01 < f23 ? f01 : f23;
    idxk = (f == 0x7fffffff) ? (NPTS - 1) : f;  // no hit anywhere -> n-1 (matches ballq)
  }
  return idxk;
}

// ---------------------------------------------------------------------------
// SA1 grouped MLP with FUSED ball query (R17). Per center (b,s): 4-wave
// quarter-scan of the 8192 points -> merged first-64 idx -> gather local
// coords -> h = relu(W1a*g+b) -> out[o] = relu(max_k (W1b[o].h[k]+b)).
// MLP phases unchanged from the verified R13 version.
// ---------------------------------------------------------------------------
__global__ __launch_bounds__(256) void sa1_kernel(
    const float* __restrict__ xyz, const float* __restrict__ ctr,
    const float* __restrict__ W1a, const float* __restrict__ b1a,
    const float* __restrict__ W1b, const float* __restrict__ b1b,
    float* __restrict__ feat) {
  __shared__ int s_hits[4 * K];
  __shared__ int s_cnt[4];
  __shared__ int s_first[4];
  __shared__ float s_l[K][3];
  __shared__ float s_h[K][64];
  __shared__ float s_red[128];
  int blk = blockIdx.x;
  int b = blk >> 9, s = blk & 511;
  int tid = threadIdx.x;
  const float* c = ctr + ((size_t)b * S1 + s) * 3;
  float cx = c[0], cy = c[1], cz = c[2];
  const float* pb = xyz + (size_t)b * N * 3;
  int idxk = ballq_fused<N>(pb, cx, cy, cz, 0.04f, tid, s_hits, s_cnt, s_first);
  if (tid < K) {
    const float* q = pb + (size_t)idxk * 3;
    s_l[tid][0] = q[0] - cx;
    s_l[tid][1] = q[1] - cy;
    s_l[tid][2] = q[2] - cz;
  }
  __syncthreads();
  for (int e = tid; e < K * 64; e += 256) {
    int k = e >> 6, o = e & 63;
    float v = b1a[o] + W1a[o * 3 + 0] * s_l[k][0] + W1a[o * 3 + 1] * s_l[k][1] +
              W1a[o * 3 + 2] * s_l[k][2];
    s_h[k][o] = fmaxf(v, 0.f);
  }
  __syncthreads();
  int o = tid & 127, half = tid >> 7;
  float w[64];
  const float4* wp = (const float4*)(W1b + o * 64);
#pragma unroll
  for (int c4 = 0; c4 < 16; c4++) {
    float4 t4 = wp[c4];
    w[c4 * 4 + 0] = t4.x; w[c4 * 4 + 1] = t4.y;
    w[c4 * 4 + 2] = t4.z; w[c4 * 4 + 3] = t4.w;
  }
  float bias = b1b[o];
  float m = -1e30f;
  int k0 = half * 32;
  for (int k = k0; k < k0 + 32; k++) {
    float acc = bias;
    const float4* hp = (const float4*)(&s_h[k][0]);
#pragma unroll
    for (int c4 = 0; c4 < 16; c4++) {
      float4 h = hp[c4];  // broadcast across the wave
      acc = fmaf(h.x, w[c4 * 4 + 0], acc);
      acc = fmaf(h.y, w[c4 * 4 + 1], acc);
      acc = fmaf(h.z, w[c4 * 4 + 2], acc);
      acc = fmaf(h.w, w[c4 * 4 + 3], acc);
    }
    m = fmaxf(m, acc);
  }
  if (half == 1) s_red[o] = m;
  __syncthreads();
  if (half == 0) {
    m = fmaxf(m, s_red[o]);
    feat[((size_t)b * S1 + s) * 128 + o] = fmaxf(m, 0.f);
  }
}

// ---------------------------------------------------------------------------
// SA2 grouped MLP with FUSED ball query (R17). Quarter = 128 pts (2 chunks).
// MLP phases (A + k-split B) unchanged from the verified R13 version.
// ---------------------------------------------------------------------------
__global__ __launch_bounds__(256) void sa2_kernel(
    const float* __restrict__ xyz1, const float* __restrict__ feat1,
    const float* __restrict__ ctr,
    const float* __restrict__ W2a, const float* __restrict__ b2a,
    const float* __restrict__ W2b, const float* __restrict__ b2b,
    float* __restrict__ in3) {
  __shared__ int s_hits[4 * K];
  __shared__ int s_cnt[4];
  __shared__ int s_first[4];
  __shared__ int s_pi[K];
  __shared__ float s_g[K][132];
  __shared__ float s_h[K][128];
  __shared__ float s_red[256];
  int blk = blockIdx.x;
  int b = blk >> 7, s = blk & 127;
  int tid = threadIdx.x;
  const float* c = ctr + ((size_t)b * S2 + s) * 3;
  float cx = c[0], cy = c[1], cz = c[2];
  const float* pb = xyz1 + (size_t)b * S1 * 3;
  int idxk = ballq_fused<S1>(pb, cx, cy, cz, 0.16f, tid, s_hits, s_cnt, s_first);
  if (tid < K) {
    s_pi[tid] = idxk;
    const float* q = pb + (size_t)idxk * 3;
    s_g[tid][0] = q[0] - cx;
    s_g[tid][1] = q[1] - cy;
    s_g[tid][2] = q[2] - cz;
  }
  __syncthreads();
  for (int e = tid; e < K * 128; e += 256) {
    int k = e >> 7, f = e & 127;
    s_g[k][3 + f] = feat1[((size_t)b * S1 + s_pi[k]) * 128 + f];
  }
  __syncthreads();
  // phase A: s_h[k][o] = relu(W2a[o] . g[k] + b2a[o])
  {
    int o = tid & 127, half = tid >> 7, k0 = half * 32;
    const float* wr = W2a + o * 131;
    float acc[32];
    float bias = b2a[o];
#pragma unroll
    for (int j = 0; j < 32; j++) acc[j] = bias;
    for (int c4 = 0; c4 < 32; c4++) {
      float w0 = wr[c4 * 4 + 0], w1 = wr[c4 * 4 + 1];
      float w2 = wr[c4 * 4 + 2], w3 = wr[c4 * 4 + 3];
#pragma unroll
      for (int j = 0; j < 32; j++) {
        float4 g = *(const float4*)(&s_g[k0 + j][c4 * 4]);
        acc[j] = fmaf(g.x, w0, acc[j]);
        acc[j] = fmaf(g.y, w1, acc[j]);
        acc[j] = fmaf(g.z, w2, acc[j]);
        acc[j] = fmaf(g.w, w3, acc[j]);
      }
    }
    float w0 = wr[128], w1 = wr[129], w2 = wr[130];
#pragma unroll
    for (int j = 0; j < 32; j++) {
      acc[j] = fmaf(s_g[k0 + j][128], w0, acc[j]);
      acc[j] = fmaf(s_g[k0 + j][129], w1, acc[j]);
      acc[j] = fmaf(s_g[k0 + j][130], w2, acc[j]);
      s_h[k0 + j][o] = fmaxf(acc[j], 0.f);
    }
  }
  __syncthreads();
  // phase B (k-split, 2 outputs/thread)
  {
    int oa = tid & 127, half = tid >> 7, k0 = half * 32;
    const float4* wpa = (const float4*)(W2b + oa * 128);
    const float4* wpb = (const float4*)(W2b + (oa + 128) * 128);
    float acca[32], accb[32];
    float ba = b2b[oa], bb = b2b[oa + 128];
#pragma unroll
    for (int j = 0; j < 32; j++) { acca[j] = ba; accb[j] = bb; }
    for (int c4 = 0; c4 < 32; c4++) {
      float4 wa = wpa[c4];
      float4 wb = wpb[c4];
#pragma unroll
      for (int j = 0; j < 32; j++) {
        float4 h = *(const float4*)(&s_h[k0 + j][c4 * 4]);
        acca[j] = fmaf(h.x, wa.x, acca[j]);
        acca[j] = fmaf(h.y, wa.y, acca[j]);
        acca[j] = fmaf(h.z, wa.z, acca[j]);
        acca[j] = fmaf(h.w, wa.w, acca[j]);
        accb[j] = fmaf(h.x, wb.x, accb[j]);
        accb[j] = fmaf(h.y, wb.y, accb[j]);
        accb[j] = fmaf(h.z, wb.z, accb[j]);
        accb[j] = fmaf(h.w, wb.w, accb[j]);
      }
    }
    float ma = -1e30f, mb = -1e30f;
#pragma unroll
    for (int j = 0; j < 32; j++) { ma = fmaxf(ma, acca[j]); mb = fmaxf(mb, accb[j]); }
    if (half == 1) { s_red[oa] = ma; s_red[oa + 128] = mb; }
    __syncthreads();
    if (half == 0) {
      ma = fmaxf(ma, s_red[oa]);
      mb = fmaxf(mb, s_red[oa + 128]);
      float* o3 = &in3[((size_t)b * S2 + s) * 259 + 3];
      o3[oa] = fmaxf(ma, 0.f);
      o3[oa + 128] = fmaxf(mb, 0.f);
    }
  }
}

// ---------------------------------------------------------------------------
// Final MLP layer a: h3[b][s][o] = relu(W3a[o] . in3[b][s] + b3a[o]).
// ---------------------------------------------------------------------------
__global__ __launch_bounds__(256) void mlp3a_kernel(
    const float* __restrict__ in3, const float* __restrict__ W3a,
    const float* __restrict__ b3a, float* __restrict__ h3) {
  __shared__ float s_wt[64][65];
  __shared__ float s_a[64][64];
  int blk = blockIdx.x;
  int b = blk >> 4, r = blk & 15;
  int ot = r >> 1, sh = r & 1;
  int tid = threadIdx.x;
  int o = tid & 63, sq = tid >> 6;
  float acc[16];
  float bias = b3a[ot * 64 + o];
#pragma unroll
  for (int j = 0; j < 16; j++) acc[j] = bias;
  for (int ch = 0; ch < 5; ch++) {
    int cb = ch * 64;
    int len = (ch == 4) ? 3 : 64;
    for (int e = tid; e < 4096; e += 256) {
      int oo = e >> 6, cc = e & 63;
      if (cc < len) s_wt[cc][oo] = W3a[(size_t)(ot * 64 + oo) * 259 + cb + cc];
    }
    for (int e = tid; e < 4096; e += 256) {
      int ss = e >> 6, cc = e & 63;
      if (cc < len) s_a[ss][cc] = in3[((size_t)b * S2 + sh * 64 + ss) * 259 + cb + cc];
    }
    __syncthreads();
    for (int cc = 0; cc < len; cc++) {
      float wv = s_wt[cc][o];
#pragma unroll
      for (int j = 0; j < 16; j++)
        acc[j] = fmaf(wv, s_a[sq * 16 + j][cc], acc[j]);
    }
    __syncthreads();
  }
#pragma unroll
  for (int j = 0; j < 16; j++) {
    int s = sh * 64 + sq * 16 + j;
    h3[((size_t)b * S2 + s) * 512 + ot * 64 + o] = fmaxf(acc[j], 0.f);
  }
}

// ---------------------------------------------------------------------------
// Final MLP layer b + global max-pool over the 128 proposals.
// ---------------------------------------------------------------------------
__global__ __launch_bounds__(256) void mlp3b_kernel(
    const float* __restrict__ h3, const float* __restrict__ W3b,
    const float* __restrict__ b3b, float* __restrict__ out) {
  __shared__ float s_wt[64][65];
  __shared__ float s_h[128][64];
  __shared__ float s_red[4][64];
  int blk = blockIdx.x;
  int b = blk >> 4, ot = blk & 15;
  int tid = threadIdx.x;
  int o = tid & 63, sq = tid >> 6;
  float acc[32];
  float bias = b3b[ot * 64 + o];
#pragma unroll
  for (int j = 0; j < 32; j++) acc[j] = bias;
  for (int ch = 0; ch < 8; ch++) {
    int cb = ch * 64;
    for (int e = tid; e < 4096; e += 256) {
      int oo = e >> 6, cc = e & 63;
      s_wt[cc][oo] = W3b[(size_t)(ot * 64 + oo) * 512 + cb + cc];
    }
    for (int e = tid; e < 8192; e += 256) {
      int ss = e >> 6, cc = e & 63;
      s_h[ss][cc] = h3[((size_t)b * S2 + ss) * 512 + cb + cc];
    }
    __syncthreads();
    for (int c4 = 0; c4 < 16; c4++) {
      float w0 = s_wt[c4 * 4 + 0][o];
      float w1 = s_wt[c4 * 4 + 1][o];
      float w2 = s_wt[c4 * 4 + 2][o];
      float w3 = s_wt[c4 * 4 + 3][o];
#pragma unroll
      for (int j = 0; j < 32; j++) {
        float4 h = *(const float4*)(&s_h[sq * 32 + j][c4 * 4]);
        acc[j] = fmaf(h.x, w0, acc[j]);
        acc[j] = fmaf(h.y, w1, acc[j]);
        acc[j] = fmaf(h.z, w2, acc[j]);
        acc[j] = fmaf(h.w, w3, acc[j]);
      }
    }
    __syncthreads();
  }
  float m = -1e30f;
#pragma unroll
  for (int j = 0; j < 32; j++) m = fmaxf(m, acc[j]);
  s_red[sq][o] = m;
  __syncthreads();
  if (sq == 0) {
    m = fmaxf(fmaxf(s_red[0][o], s_red[1][o]), fmaxf(s_red[2][o], s_red[3][o]));
    out[(size_t)b * 1024 + ot * 64 + o] = fmaxf(m, 0.f);
  }
}

extern "C" void kernel_launch(void* const* d_in, const int* in_sizes, int n_in,
                              void* d_out, int out_size, void* d_ws, size_t ws_size,
                              hipStream_t stream) {
  const float* x = (const float*)d_in[0];
  const float* W1a = (const float*)d_in[1];
  const float* b1a = (const float*)d_in[2];
  const float* W1b = (const float*)d_in[3];
  const float* b1b = (const float*)d_in[4];
  const float* W2a = (const float*)d_in[5];
  const float* b2a = (const float*)d_in[6];
  const float* W2b = (const float*)d_in[7];
  const float* b2b = (const float*)d_in[8];
  const float* W3a = (const float*)d_in[9];
  const float* b3a = (const float*)d_in[10];
  const float* W3b = (const float*)d_in[11];
  const float* b3b = (const float*)d_in[12];
  float* out = (float*)d_out;

  // workspace carve (idx buffers no longer needed — ballq fused into SA)
  float* nx1 = (float*)d_ws;                       // [16,512,3]
  float* feat1 = nx1 + 16 * 512 * 3;               // [16,512,128]
  float* nx2 = feat1 + 16 * 512 * 128;             // [16,128,3]
  float* in3 = nx2 + 16 * 128 * 3;                 // [16,128,259] = [xyz2|feat2]
  float* h3 = in3 + 16 * 128 * 259;                // [16,128,512]

  fps1_kernel<<<B, 1024, 0, stream>>>(x, nx1, nullptr, 0, N, S1);
  sa1_kernel<<<B * S1, 256, 0, stream>>>(x, nx1, W1a, b1a, W1b, b1b, feat1);
  fps_wave_kernel<8, 128, 512><<<B, 64, 0, stream>>>(nx1, nx2, in3, 259, S1, S2);
  sa2_kernel<<<B * S2, 256, 0, stream>>>(nx1, feat1, nx2, W2a, b2a, W2b, b2b, in3);
  mlp3a_kernel<<<256, 256, 0, stream>>>(in3, W3a, b3a, h3);
  mlp3b_kernel<<<256, 256, 0, stream>>>(h3, W3b, b3b, out);
}

// Round 11
// 1211.679 us; speedup vs baseline: 1.2223x; 1.2223x over previous
//
#include <hip/hip_runtime.h>

#define B 16
#define N 8192
#define S1 512
#define S2 128
#define K 64

// ---------------------------------------------------------------------------
// DPP max step: wm = max(wm, dpp_shift(wm)). Value-only.
// ---------------------------------------------------------------------------
template<int CTRL>
__device__ __forceinline__ float dpp_max_f32(float v) {
  unsigned o = (unsigned)__builtin_amdgcn_update_dpp(
      (int)__float_as_uint(v), (int)__float_as_uint(v), CTRL, 0xF, 0xF, false);
  return fmaxf(v, __uint_as_float(o));
}

__device__ __forceinline__ float wave_max_bcast(float v) {
  v = dpp_max_f32<0x111>(v);  // row_shr:1
  v = dpp_max_f32<0x112>(v);  // row_shr:2
  v = dpp_max_f32<0x114>(v);  // row_shr:4
  v = dpp_max_f32<0x118>(v);  // row_shr:8
  v = dpp_max_f32<0x142>(v);  // row_bcast:15
  v = dpp_max_f32<0x143>(v);  // row_bcast:31 -> lane 63 holds wave max
  return __uint_as_float((unsigned)__builtin_amdgcn_readlane(
      (int)__float_as_uint(v), 63));  // SGPR broadcast to all lanes
}

// ---------------------------------------------------------------------------
// FPS stage 1 (multi-wave), FROZEN at the proven R13 config (450us, VGPR 52).
// ROUND-18 (R17 post-mortem): ballq fusion REVERTED — quarter-scan did 4x
// the scan work (density ~274 hits/8192 means a wave needs ~1900 pts for 64
// hits; each quarter-wave scanned ~1900 of its 2048 instead of one wave
// scanning ~1900 total). sa1_fused measured 497us, worst dispatch.
// ---------------------------------------------------------------------------
template<int NT, int PT, int MAXP, int MAXN>
__device__ __forceinline__ void fps_body(
    const float* __restrict__ pts, float* __restrict__ out_xyz,
    float* __restrict__ out2, int out2_stride, int n, int npoint) {
  const int b = blockIdx.x;
  const int t = threadIdx.x;
  const int w = t >> 6;
  const float* base = pts + (size_t)b * n * 3;
  __shared__ unsigned long long cell[3][4];
  __shared__ float s_out[MAXP * 3];
  __shared__ float s_pts[MAXN * 3];
  if (t < 12) ((unsigned long long*)cell)[t] = 0ull;
  float px[PT], py[PT], pz[PT], mind[PT];
#pragma unroll
  for (int i = 0; i < PT; i++) {
    int p = t + i * NT;
    px[i] = base[p * 3 + 0];
    py[i] = base[p * 3 + 1];
    pz[i] = base[p * 3 + 2];
    mind[i] = 1e10f;
    s_pts[p * 3 + 0] = px[i];
    s_pts[p * 3 + 1] = py[i];
    s_pts[p * 3 + 2] = pz[i];
  }
  float cx = base[0], cy = base[1], cz = base[2];
  __syncthreads();
  for (int it = 0; it < npoint; it++) {
    if (t == 0) {
      s_out[it * 3 + 0] = cx; s_out[it * 3 + 1] = cy; s_out[it * 3 + 2] = cz;
    }
    float bv = -1.0f;
#pragma unroll
    for (int i = 0; i < PT; i++) {
      float dx = px[i] - cx, dy = py[i] - cy, dz = pz[i] - cz;
      float d = dx * dx;
      d = fmaf(dy, dy, d);
      d = fmaf(dz, dz, d);
      float md = fminf(mind[i], d);
      mind[i] = md;
      bv = fmaxf(bv, md);
    }
    float gm = wave_max_bcast(bv);
    if (bv == gm) {
      int bi = 0;
#pragma unroll
      for (int i = PT - 1; i >= 0; i--)
        if (mind[i] == bv) bi = i;  // downward sweep -> smallest i survives
      unsigned long long kk = ((unsigned long long)__float_as_uint(bv) << 32) |
                              (~(unsigned)(t + bi * NT));
      atomicMax(&cell[it % 3][w & 3], kk);
    }
    if (t < 4) cell[(it + 1) % 3][t] = 0ull;
    __syncthreads();
    unsigned long long k0 = cell[it % 3][0];
    unsigned long long k1 = cell[it % 3][1];
    unsigned long long k2 = cell[it % 3][2];
    unsigned long long k3 = cell[it % 3][3];
    unsigned long long wk = k0 > k1 ? k0 : k1;
    unsigned long long wk2 = k2 > k3 ? k2 : k3;
    if (wk2 > wk) wk = wk2;
    int ui = __builtin_amdgcn_readfirstlane((int)(~(unsigned)wk));
    const float* q = s_pts + ui * 3;
    cx = q[0]; cy = q[1]; cz = q[2];
  }
  for (int e = t; e < npoint * 3; e += NT)
    out_xyz[(size_t)b * npoint * 3 + e] = s_out[e];
  if (out2) {
    for (int e = t; e < npoint; e += NT) {
      float* o2 = out2 + ((size_t)b * npoint + e) * out2_stride;
      o2[0] = s_out[e * 3 + 0];
      o2[1] = s_out[e * 3 + 1];
      o2[2] = s_out[e * 3 + 2];
    }
  }
}

__global__ __launch_bounds__(1024) __attribute__((amdgpu_waves_per_eu(4, 4)))
void fps1_kernel(const float* __restrict__ pts, float* __restrict__ out_xyz,
                 float* __restrict__ out2, int out2_stride, int n, int npoint) {
  fps_body<1024, 8, 512, 8192>(pts, out_xyz, out2, out2_stride, n, npoint);
}

// ---------------------------------------------------------------------------
// FPS stage 2 — single wave, barrier-free (R16, verified).
// ---------------------------------------------------------------------------
template<int PT, int MAXP, int MAXN>
__global__ __launch_bounds__(64) __attribute__((amdgpu_waves_per_eu(1, 1)))
void fps_wave_kernel(const float* __restrict__ pts, float* __restrict__ out_xyz,
                     float* __restrict__ out2, int out2_stride, int n, int npoint) {
  const int b = blockIdx.x;
  const int t = threadIdx.x;
  const float* base = pts + (size_t)b * n * 3;
  __shared__ unsigned long long cell[2];
  __shared__ float s_out[MAXP * 3];
  __shared__ float s_pts[MAXN * 3];
  if (t < 2) cell[t] = 0ull;
  float px[PT], py[PT], pz[PT], mind[PT];
#pragma unroll
  for (int i = 0; i < PT; i++) {
    int p = t + i * 64;
    px[i] = base[p * 3 + 0];
    py[i] = base[p * 3 + 1];
    pz[i] = base[p * 3 + 2];
    mind[i] = 1e10f;
    s_pts[p * 3 + 0] = px[i];
    s_pts[p * 3 + 1] = py[i];
    s_pts[p * 3 + 2] = pz[i];
  }
  float cx = base[0], cy = base[1], cz = base[2];
  for (int it = 0; it < npoint; it++) {
    if (t == 0) {
      s_out[it * 3 + 0] = cx; s_out[it * 3 + 1] = cy; s_out[it * 3 + 2] = cz;
    }
    float bv = -1.0f;
#pragma unroll
    for (int i = 0; i < PT; i++) {
      float dx = px[i] - cx, dy = py[i] - cy, dz = pz[i] - cz;
      float d = dx * dx;
      d = fmaf(dy, dy, d);
      d = fmaf(dz, dz, d);
      float md = fminf(mind[i], d);
      mind[i] = md;
      bv = fmaxf(bv, md);
    }
    float gm = wave_max_bcast(bv);
    if (bv == gm) {
      int bi = 0;
#pragma unroll
      for (int i = PT - 1; i >= 0; i--)
        if (mind[i] == bv) bi = i;
      unsigned long long kk = ((unsigned long long)__float_as_uint(bv) << 32) |
                              (~(unsigned)(t + bi * 64));
      atomicMax(&cell[it & 1], kk);
    }
    __threadfence_block();
    unsigned long long wk = cell[it & 1];
    if (t == 0) cell[(it + 1) & 1] = 0ull;
    int ui = __builtin_amdgcn_readfirstlane((int)(~(unsigned)wk));
    const float* q = s_pts + ui * 3;
    cx = q[0]; cy = q[1]; cz = q[2];
  }
  for (int e = t; e < npoint * 3; e += 64)
    out_xyz[(size_t)b * npoint * 3 + e] = s_out[e];
  if (out2) {
    for (int e = t; e < npoint; e += 64) {
      float* o2 = out2 + ((size_t)b * npoint + e) * out2_stride;
      o2[0] = s_out[e * 3 + 0];
      o2[1] = s_out[e * 3 + 1];
      o2[2] = s_out[e * 3 + 2];
    }
  }
}

// ---------------------------------------------------------------------------
// Ball query (standalone, R17 revert): one wave per center; ballot-scan in
// index order, first K in-radius; tail filled with first hit (or n-1).
// ---------------------------------------------------------------------------
__global__ __launch_bounds__(256) void ballq_kernel(
    const float* __restrict__ pts, const float* __restrict__ ctr,
    int* __restrict__ idx, int n, int ns, int total, float r2) {
  int gid = blockIdx.x * blockDim.x + threadIdx.x;
  int wid = gid >> 6;
  int lane = threadIdx.x & 63;
  if (wid >= total) return;
  int b = wid / ns, s = wid - b * ns;
  const float* pb = pts + (size_t)b * n * 3;
  const float* c = ctr + ((size_t)b * ns + s) * 3;
  float cx = c[0], cy = c[1], cz = c[2];
  float sc = cx * cx + cy * cy + cz * cz;
  int* out = idx + ((size_t)b * ns + s) * K;
  int cnt = 0, first = n - 1;
  for (int base = 0; base < n && cnt < K; base += 64) {
    int p = base + lane;
    float x = pb[p * 3 + 0], y = pb[p * 3 + 1], z = pb[p * 3 + 2];
    float sp = x * x + y * y + z * z;
    float dot = cx * x + cy * y + cz * z;
    float d2 = sc + sp - 2.0f * dot;
    bool inr = d2 < r2;
    unsigned long long m = __ballot(inr);
    if (cnt == 0 && m != 0ull) first = base + __ffsll((long long)m) - 1;
    int pre = (int)__popcll(m & ((1ull << lane) - 1ull));
    if (inr && (cnt + pre) < K) out[cnt + pre] = p;
    cnt += (int)__popcll(m);
  }
  if (cnt > K) cnt = K;
  if (lane >= cnt) out[lane] = first;
}

// ---------------------------------------------------------------------------
// SA1 grouped MLP. ROUND-18: phase 2 restructured like sa2's phase B —
// theory: old phase 2 issued 512 ds_read_b128 broadcasts per thread feeding
// only 2048 fma (1:4); at ~12 cyc/b128 the DS pipe (not VALU) bounds the
// kernel. New: 256 threads = 64 output-pairs (oa, oa+64) x 4 k-quarters of
// 16; each h-read feeds 8 fma (reads halved to 256/thread, 1:8); weights
// read per-c4 from L1-resident W1b (32 KB). Per-(o,k) fma chain bit-identical
// (same c4/xyzw order, same bias start); max over k exact under regrouping
// (quarter maxes combined via LDS).
// ---------------------------------------------------------------------------
__global__ __launch_bounds__(256) void sa1_kernel(
    const float* __restrict__ xyz, const int* __restrict__ idx,
    const float* __restrict__ ctr, const float* __restrict__ W1a,
    const float* __restrict__ b1a, const float* __restrict__ W1b,
    const float* __restrict__ b1b, float* __restrict__ feat) {
  __shared__ float s_l[K][3];
  __shared__ float s_h[K][64];
  __shared__ float s_red[4][128];
  int blk = blockIdx.x;
  int b = blk >> 9, s = blk & 511;
  int tid = threadIdx.x;
  const int* gi = idx + ((size_t)b * S1 + s) * K;
  const float* c = ctr + ((size_t)b * S1 + s) * 3;
  float cx = c[0], cy = c[1], cz = c[2];
  if (tid < K) {
    int p = gi[tid];
    const float* q = xyz + ((size_t)b * N + p) * 3;
    s_l[tid][0] = q[0] - cx;
    s_l[tid][1] = q[1] - cy;
    s_l[tid][2] = q[2] - cz;
  }
  __syncthreads();
  for (int e = tid; e < K * 64; e += 256) {
    int k = e >> 6, o = e & 63;
    float v = b1a[o] + W1a[o * 3 + 0] * s_l[k][0] + W1a[o * 3 + 1] * s_l[k][1] +
              W1a[o * 3 + 2] * s_l[k][2];
    s_h[k][o] = fmaxf(v, 0.f);
  }
  __syncthreads();
  // phase 2: outputs (oa, oa+64), k-quarter [k0, k0+16)
  {
    int oa = tid & 63, kq = tid >> 6, k0 = kq * 16;
    const float4* wpa = (const float4*)(W1b + oa * 64);          // 256B-aligned
    const float4* wpb = (const float4*)(W1b + (oa + 64) * 64);
    float ba = b1b[oa], bb = b1b[oa + 64];
    float acca[16], accb[16];
#pragma unroll
    for (int j = 0; j < 16; j++) { acca[j] = ba; accb[j] = bb; }
    for (int c4 = 0; c4 < 16; c4++) {
      float4 wa = wpa[c4];
      float4 wb = wpb[c4];
#pragma unroll
      for (int j = 0; j < 16; j++) {
        float4 h = *(const float4*)(&s_h[k0 + j][c4 * 4]);  // broadcast; feeds 8 fma
        acca[j] = fmaf(h.x, wa.x, acca[j]);
        acca[j] = fmaf(h.y, wa.y, acca[j]);
        acca[j] = fmaf(h.z, wa.z, acca[j]);
        acca[j] = fmaf(h.w, wa.w, acca[j]);
        accb[j] = fmaf(h.x, wb.x, accb[j]);
        accb[j] = fmaf(h.y, wb.y, accb[j]);
        accb[j] = fmaf(h.z, wb.z, accb[j]);
        accb[j] = fmaf(h.w, wb.w, accb[j]);
      }
    }
    float ma = -1e30f, mb = -1e30f;
#pragma unroll
    for (int j = 0; j < 16; j++) { ma = fmaxf(ma, acca[j]); mb = fmaxf(mb, accb[j]); }
    s_red[kq][oa] = ma;
    s_red[kq][oa + 64] = mb;
  }
  __syncthreads();
  if (tid < 128) {
    float m = fmaxf(fmaxf(s_red[0][tid], s_red[1][tid]),
                    fmaxf(s_red[2][tid], s_red[3][tid]));
    feat[((size_t)b * S1 + s) * 128 + tid] = fmaxf(m, 0.f);  // relu(max)==max(relu)
  }
}

// ---------------------------------------------------------------------------
// SA2 grouped MLP (standalone idx input; phase B k-split verified R13).
// ---------------------------------------------------------------------------
__global__ __launch_bounds__(256) void sa2_kernel(
    const float* __restrict__ xyz1, const float* __restrict__ feat1,
    const int* __restrict__ idx, const float* __restrict__ ctr,
    const float* __restrict__ W2a, const float* __restrict__ b2a,
    const float* __restrict__ W2b, const float* __restrict__ b2b,
    float* __restrict__ in3) {
  __shared__ int s_pi[K];
  __shared__ float s_g[K][132];
  __shared__ float s_h[K][128];
  __shared__ float s_red[256];
  int blk = blockIdx.x;
  int b = blk >> 7, s = blk & 127;
  int tid = threadIdx.x;
  const int* gi = idx + ((size_t)b * S2 + s) * K;
  const float* c = ctr + ((size_t)b * S2 + s) * 3;
  float cx = c[0], cy = c[1], cz = c[2];
  if (tid < K) {
    int p = gi[tid];
    s_pi[tid] = p;
    const float* q = xyz1 + ((size_t)b * S1 + p) * 3;
    s_g[tid][0] = q[0] - cx;
    s_g[tid][1] = q[1] - cy;
    s_g[tid][2] = q[2] - cz;
  }
  __syncthreads();
  for (int e = tid; e < K * 128; e += 256) {
    int k = e >> 7, f = e & 127;
    s_g[k][3 + f] = feat1[((size_t)b * S1 + s_pi[k]) * 128 + f];
  }
  __syncthreads();
  // phase A
  {
    int o = tid & 127, half = tid >> 7, k0 = half * 32;
    const float* wr = W2a + o * 131;
    float acc[32];
    float bias = b2a[o];
#pragma unroll
    for (int j = 0; j < 32; j++) acc[j] = bias;
    for (int c4 = 0; c4 < 32; c4++) {
      float w0 = wr[c4 * 4 + 0], w1 = wr[c4 * 4 + 1];
      float w2 = wr[c4 * 4 + 2], w3 = wr[c4 * 4 + 3];
#pragma unroll
      for (int j = 0; j < 32; j++) {
        float4 g = *(const float4*)(&s_g[k0 + j][c4 * 4]);
        acc[j] = fmaf(g.x, w0, acc[j]);
        acc[j] = fmaf(g.y, w1, acc[j]);
        acc[j] = fmaf(g.z, w2, acc[j]);
        acc[j] = fmaf(g.w, w3, acc[j]);
      }
    }
    float w0 = wr[128], w1 = wr[129], w2 = wr[130];
#pragma unroll
    for (int j = 0; j < 32; j++) {
      acc[j] = fmaf(s_g[k0 + j][128], w0, acc[j]);
      acc[j] = fmaf(s_g[k0 + j][129], w1, acc[j]);
      acc[j] = fmaf(s_g[k0 + j][130], w2, acc[j]);
      s_h[k0 + j][o] = fmaxf(acc[j], 0.f);
    }
  }
  __syncthreads();
  // phase B (k-split, 2 outputs/thread)
  {
    int oa = tid & 127, half = tid >> 7, k0 = half * 32;
    const float4* wpa = (const float4*)(W2b + oa * 128);
    const float4* wpb = (const float4*)(W2b + (oa + 128) * 128);
    float acca[32], accb[32];
    float ba = b2b[oa], bb = b2b[oa + 128];
#pragma unroll
    for (int j = 0; j < 32; j++) { acca[j] = ba; accb[j] = bb; }
    for (int c4 = 0; c4 < 32; c4++) {
      float4 wa = wpa[c4];
      float4 wb = wpb[c4];
#pragma unroll
      for (int j = 0; j < 32; j++) {
        float4 h = *(const float4*)(&s_h[k0 + j][c4 * 4]);
        acca[j] = fmaf(h.x, wa.x, acca[j]);
        acca[j] = fmaf(h.y, wa.y, acca[j]);
        acca[j] = fmaf(h.z, wa.z, acca[j]);
        acca[j] = fmaf(h.w, wa.w, acca[j]);
        accb[j] = fmaf(h.x, wb.x, accb[j]);
        accb[j] = fmaf(h.y, wb.y, accb[j]);
        accb[j] = fmaf(h.z, wb.z, accb[j]);
        accb[j] = fmaf(h.w, wb.w, accb[j]);
      }
    }
    float ma = -1e30f, mb = -1e30f;
#pragma unroll
    for (int j = 0; j < 32; j++) { ma = fmaxf(ma, acca[j]); mb = fmaxf(mb, accb[j]); }
    if (half == 1) { s_red[oa] = ma; s_red[oa + 128] = mb; }
    __syncthreads();
    if (half == 0) {
      ma = fmaxf(ma, s_red[oa]);
      mb = fmaxf(mb, s_red[oa + 128]);
      float* o3 = &in3[((size_t)b * S2 + s) * 259 + 3];
      o3[oa] = fmaxf(ma, 0.f);
      o3[oa + 128] = fmaxf(mb, 0.f);
    }
  }
}

// ---------------------------------------------------------------------------
// Final MLP layer a: h3[b][s][o] = relu(W3a[o] . in3[b][s] + b3a[o]).
// ---------------------------------------------------------------------------
__global__ __launch_bounds__(256) void mlp3a_kernel(
    const float* __restrict__ in3, const float* __restrict__ W3a,
    const float* __restrict__ b3a, float* __restrict__ h3) {
  __shared__ float s_wt[64][65];
  __shared__ float s_a[64][64];
  int blk = blockIdx.x;
  int b = blk >> 4, r = blk & 15;
  int ot = r >> 1, sh = r & 1;
  int tid = threadIdx.x;
  int o = tid & 63, sq = tid >> 6;
  float acc[16];
  float bias = b3a[ot * 64 + o];
#pragma unroll
  for (int j = 0; j < 16; j++) acc[j] = bias;
  for (int ch = 0; ch < 5; ch++) {
    int cb = ch * 64;
    int len = (ch == 4) ? 3 : 64;
    for (int e = tid; e < 4096; e += 256) {
      int oo = e >> 6, cc = e & 63;
      if (cc < len) s_wt[cc][oo] = W3a[(size_t)(ot * 64 + oo) * 259 + cb + cc];
    }
    for (int e = tid; e < 4096; e += 256) {
      int ss = e >> 6, cc = e & 63;
      if (cc < len) s_a[ss][cc] = in3[((size_t)b * S2 + sh * 64 + ss) * 259 + cb + cc];
    }
    __syncthreads();
    for (int cc = 0; cc < len; cc++) {
      float wv = s_wt[cc][o];
#pragma unroll
      for (int j = 0; j < 16; j++)
        acc[j] = fmaf(wv, s_a[sq * 16 + j][cc], acc[j]);
    }
    __syncthreads();
  }
#pragma unroll
  for (int j = 0; j < 16; j++) {
    int s = sh * 64 + sq * 16 + j;
    h3[((size_t)b * S2 + s) * 512 + ot * 64 + o] = fmaxf(acc[j], 0.f);
  }
}

// ---------------------------------------------------------------------------
// Final MLP layer b + global max-pool over the 128 proposals.
// ---------------------------------------------------------------------------
__global__ __launch_bounds__(256) void mlp3b_kernel(
    const float* __restrict__ h3, const float* __restrict__ W3b,
    const float* __restrict__ b3b, float* __restrict__ out) {
  __shared__ float s_wt[64][65];
  __shared__ float s_h[128][64];
  __shared__ float s_red[4][64];
  int blk = blockIdx.x;
  int b = blk >> 4, ot = blk & 15;
  int tid = threadIdx.x;
  int o = tid & 63, sq = tid >> 6;
  float acc[32];
  float bias = b3b[ot * 64 + o];
#pragma unroll
  for (int j = 0; j < 32; j++) acc[j] = bias;
  for (int ch = 0; ch < 8; ch++) {
    int cb = ch * 64;
    for (int e = tid; e < 4096; e += 256) {
      int oo = e >> 6, cc = e & 63;
      s_wt[cc][oo] = W3b[(size_t)(ot * 64 + oo) * 512 + cb + cc];
    }
    for (int e = tid; e < 8192; e += 256) {
      int ss = e >> 6, cc = e & 63;
      s_h[ss][cc] = h3[((size_t)b * S2 + ss) * 512 + cb + cc];
    }
    __syncthreads();
    for (int c4 = 0; c4 < 16; c4++) {
      float w0 = s_wt[c4 * 4 + 0][o];
      float w1 = s_wt[c4 * 4 + 1][o];
      float w2 = s_wt[c4 * 4 + 2][o];
      float w3 = s_wt[c4 * 4 + 3][o];
#pragma unroll
      for (int j = 0; j < 32; j++) {
        float4 h = *(const float4*)(&s_h[sq * 32 + j][c4 * 4]);
        acc[j] = fmaf(h.x, w0, acc[j]);
        acc[j] = fmaf(h.y, w1, acc[j]);
        acc[j] = fmaf(h.z, w2, acc[j]);
        acc[j] = fmaf(h.w, w3, acc[j]);
      }
    }
    __syncthreads();
  }
  float m = -1e30f;
#pragma unroll
  for (int j = 0; j < 32; j++) m = fmaxf(m, acc[j]);
  s_red[sq][o] = m;
  __syncthreads();
  if (sq == 0) {
    m = fmaxf(fmaxf(s_red[0][o], s_red[1][o]), fmaxf(s_red[2][o], s_red[3][o]));
    out[(size_t)b * 1024 + ot * 64 + o] = fmaxf(m, 0.f);
  }
}

extern "C" void kernel_launch(void* const* d_in, const int* in_sizes, int n_in,
                              void* d_out, int out_size, void* d_ws, size_t ws_size,
                              hipStream_t stream) {
  const float* x = (const float*)d_in[0];
  const float* W1a = (const float*)d_in[1];
  const float* b1a = (const float*)d_in[2];
  const float* W1b = (const float*)d_in[3];
  const float* b1b = (const float*)d_in[4];
  const float* W2a = (const float*)d_in[5];
  const float* b2a = (const float*)d_in[6];
  const float* W2b = (const float*)d_in[7];
  const float* b2b = (const float*)d_in[8];
  const float* W3a = (const float*)d_in[9];
  const float* b3a = (const float*)d_in[10];
  const float* W3b = (const float*)d_in[11];
  const float* b3b = (const float*)d_in[12];
  float* out = (float*)d_out;

  // workspace carve (floats/ints; all segments 16B-aligned) — ~13.3 MB total
  float* nx1 = (float*)d_ws;                       // [16,512,3]
  int* idx1 = (int*)(nx1 + 16 * 512 * 3);          // [16,512,64]
  float* feat1 = (float*)(idx1 + 16 * 512 * 64);   // [16,512,128]
  float* nx2 = feat1 + 16 * 512 * 128;             // [16,128,3]
  int* idx2 = (int*)(nx2 + 16 * 128 * 3);          // [16,128,64]
  float* in3 = (float*)(idx2 + 16 * 128 * 64);     // [16,128,259] = [xyz2|feat2]
  float* h3 = in3 + 16 * 128 * 259;                // [16,128,512]

  fps1_kernel<<<B, 1024, 0, stream>>>(x, nx1, nullptr, 0, N, S1);
  ballq_kernel<<<(B * S1) / 4, 256, 0, stream>>>(x, nx1, idx1, N, S1, B * S1, 0.04f);
  sa1_kernel<<<B * S1, 256, 0, stream>>>(x, idx1, nx1, W1a, b1a, W1b, b1b, feat1);
  fps_wave_kernel<8, 128, 512><<<B, 64, 0, stream>>>(nx1, nx2, in3, 259, S1, S2);
  ballq_kernel<<<(B * S2) / 4, 256, 0, stream>>>(nx1, nx2, idx2, S1, S2, B * S2, 0.16f);
  sa2_kernel<<<B * S2, 256, 0, stream>>>(nx1, feat1, idx2, nx2, W2a, b2a, W2b, b2b, in3);
  mlp3a_kernel<<<256, 256, 0, stream>>>(in3, W3a, b3a, h3);
  mlp3b_kernel<<<256, 256, 0, stream>>>(h3, W3b, b3b, out);
}